// Round 1
// 261.906 us; speedup vs baseline: 1.0608x; 1.0608x over previous
//
#include <hip/hip_runtime.h>

// (B,C,H,W) = (4,16,320,640), fp32 throughout.
constexpr int Bn = 4;
constexpr int Cn = 16;
constexpr int Hn = 320;
constexpr int Wn = 640;
constexpr int NCOL = Bn * Cn * Wn;   // 40960 vertical columns
constexpr int NROW = Bn * Cn * Hn;   // 20480 horizontal rows

// ---------------------------------------------------------------------------
// Vertical, both directions fused fully in registers, ONE store.
// Block = 1024 threads = 16 waves; wave s owns rows [s*20, s*20+20) of the
// same 64 consecutive columns, for BOTH directions. DOWN: local scan into
// rd/P regs, LDS carry stitch, fixup in regs (no store). UP: same rows,
// reverse local scan reusing the register-resident x, reverse stitch, then a
// single coalesced store of max(r_down, r_up). No vm readback, no RMW.
// __launch_bounds__(1024, 4): 128-VGPR cap so the 4x20-float register state
// (xl, rd, yu, Pu) stays in VGPRs — the previous (1024, 8) capped at 64 and
// spilled the scan arrays to scratch (VGPR_Count=32 in rocprof).
// Recurrence: y = g*y_prev + x*(1-g) == fma(g, y_prev - x, x); g:=0 at head.
// ---------------------------------------------------------------------------
constexpr int HS = 20;               // rows per segment (320 = 16*20)
constexpr int NS = 16;               // segments = waves per block
constexpr int GPW = Wn / 64;         // 10 column-groups per image width

__global__ __launch_bounds__(1024, 4) void vert_both(
    const float* __restrict__ x, const float* __restrict__ g0,
    const float* __restrict__ g1, float* __restrict__ vm) {
  __shared__ float As[NS][64], Bs[NS][64];
  const int grp = blockIdx.x;              // 640 groups
  const int bc = grp / GPW;
  const int w0 = (grp % GPW) * 64;
  const int s = threadIdx.x >> 6;
  const int l = threadIdx.x & 63;
  const int colbase = bc * (Hn * Wn) + w0 + l;   // < 2^24, int is fine
  const int base = colbase + (s * HS) * Wn;

  float xl[HS];   // x, register-resident, reused by both directions
  float rd[HS];   // DOWN: local y, then fixed-up r_down
  float yu[HS];   // DOWN: local prefix-product P; UP: local y
  float Pu[HS];   // UP: local prefix-product P

  // ================= DOWN (g0, rows ascending) =================
  {
    int off = base;
    float yy = 0.0f, pp = 1.0f;
#pragma unroll
    for (int i = 0; i < HS; ++i) {
      xl[i] = x[off];
      float gv = g0[off];
      float bb = (s == 0 && i == 0) ? 0.0f : gv;
      yy = fmaf(bb, yy - xl[i], xl[i]);
      pp *= bb;
      rd[i] = yy;
      yu[i] = pp;                          // P_down parked in yu
      off += Wn;
    }
    As[s][l] = yy;
    Bs[s][l] = pp;
  }
  __syncthreads();
  if (threadIdx.x < 64) {                  // wave 0: serial carry stitch
    float c = 0.0f;
#pragma unroll
    for (int ss = 0; ss < NS; ++ss) {
      float a = As[ss][l], b = Bs[ss][l];
      As[ss][l] = c;                       // carry-in for segment ss
      c = fmaf(b, c, a);
    }
  }
  __syncthreads();
  {
    float c = As[s][l];                    // own row of As; safe to overwrite
#pragma unroll                             // below (same thread, program order)
    for (int i = 0; i < HS; ++i) rd[i] = fmaf(yu[i], c, rd[i]);
  }

  // ================= UP (g1, same rows, descending) =================
  {
    int off = base + (HS - 1) * Wn;
    float yy = 0.0f, pp = 1.0f;
#pragma unroll
    for (int i = HS - 1; i >= 0; --i) {
      float gv = g1[off];
      float bb = (s == NS - 1 && i == HS - 1) ? 0.0f : gv;
      yy = fmaf(bb, yy - xl[i], xl[i]);
      pp *= bb;
      yu[i] = yy;
      Pu[i] = pp;
      off -= Wn;
    }
    As[s][l] = yy;                         // own row only; cross-wave reads of
    Bs[s][l] = pp;                         // the old value were pre-barrier
  }
  __syncthreads();
  if (threadIdx.x < 64) {                  // wave 0: reverse carry stitch
    float c = 0.0f;
#pragma unroll
    for (int ss = NS - 1; ss >= 0; --ss) {
      float a = As[ss][l], b = Bs[ss][l];
      As[ss][l] = c;                       // carry-in for segment ss (from below)
      c = fmaf(b, c, a);
    }
  }
  __syncthreads();
  {
    float c = As[s][l];
    int off = base;
#pragma unroll
    for (int i = 0; i < HS; ++i) {
      float u = fmaf(Pu[i], c, yu[i]);     // r_up
      vm[off] = fmaxf(rd[i], u);           // single store of max(r_down, r_up)
      off += Wn;
    }
  }
}

// ---------------------------------------------------------------------------
// Horizontal + final: block = 256 threads = 4 waves, 4 consecutive rows.
// Stage x/g2/g3 into LDS with coalesced float4 loads; prefetch vm(=out) into
// registers at the same time. One wave per row does the lane-segmented scan
// (WSEG=10) from LDS with one 6-step shuffle scan of (A,B) per direction.
// Final: out = max(r_right, r_left, vm) — same lines this block read.
// ---------------------------------------------------------------------------
constexpr int WSEG = 10;                   // 64 lanes * 10 = 640

__global__ __launch_bounds__(256) void horiz_final(
    const float* __restrict__ x, const float* __restrict__ g2,
    const float* __restrict__ g3, const float* __restrict__ vm,
    float* __restrict__ out) {
  __shared__ float xs[4 * Wn], rrs[4 * Wn], rls[4 * Wn];   // 30 KB
  const int tid = threadIdx.x, wv = tid >> 6, l = tid & 63;
  const size_t rowbase = (size_t)blockIdx.x * 4 * Wn;      // 4 rows contiguous

  const float4* xg = (const float4*)(x + rowbase);
  const float4* g2g = (const float4*)(g2 + rowbase);
  const float4* g3g = (const float4*)(g3 + rowbase);
  const float4* vm4 = (const float4*)(vm + rowbase);
  float4* xsv = (float4*)xs;
  float4* rrv = (float4*)rrs;
  float4* rlv = (float4*)rls;

  // ---- stage (coalesced float4); vm prefetched into registers ----
  const int i0 = tid, i1 = tid + 256, i2 = tid + 512;      // i2 valid if tid<128
  float4 v0, v1, v2;
  xsv[i0] = xg[i0]; rrv[i0] = g2g[i0]; rlv[i0] = g3g[i0]; v0 = vm4[i0];
  xsv[i1] = xg[i1]; rrv[i1] = g2g[i1]; rlv[i1] = g3g[i1]; v1 = vm4[i1];
  if (i2 < Wn) { xsv[i2] = xg[i2]; rrv[i2] = g2g[i2]; rlv[i2] = g3g[i2]; v2 = vm4[i2]; }
  __syncthreads();

  const int rb = wv * Wn + l * WSEG;
  float xl[WSEG], gl[WSEG], yl[WSEG], pl[WSEG];
#pragma unroll
  for (int i = 0; i < WSEG; ++i) { xl[i] = xs[rb + i]; gl[i] = rrs[rb + i]; }

  // ---- forward (r_right) ----
  {
    float y = 0.0f, p = 1.0f;
#pragma unroll
    for (int i = 0; i < WSEG; ++i) {
      float bb = (l == 0 && i == 0) ? 0.0f : gl[i];
      y = fmaf(bb, y - xl[i], xl[i]);
      p *= bb;
      yl[i] = y; pl[i] = p;
    }
    float A = y, B = p;
#pragma unroll
    for (int off = 1; off < 64; off <<= 1) {
      float Au = __shfl_up(A, off);
      float Bu = __shfl_up(B, off);
      if (l >= off) { A = fmaf(B, Au, A); B *= Bu; }
    }
    float c = __shfl_up(A, 1);
    if (l == 0) c = 0.0f;
#pragma unroll
    for (int i = 0; i < WSEG; ++i) rrs[rb + i] = fmaf(pl[i], c, yl[i]);
  }

  // ---- backward (r_left) ----
#pragma unroll
  for (int i = 0; i < WSEG; ++i) gl[i] = rls[rb + i];
  {
    float y = 0.0f, p = 1.0f;
#pragma unroll
    for (int i = WSEG - 1; i >= 0; --i) {
      float bb = (l == 63 && i == WSEG - 1) ? 0.0f : gl[i];
      y = fmaf(bb, y - xl[i], xl[i]);
      p *= bb;
      yl[i] = y; pl[i] = p;
    }
    float A = y, B = p;
#pragma unroll
    for (int off = 1; off < 64; off <<= 1) {
      float Ad = __shfl_down(A, off);
      float Bd = __shfl_down(B, off);
      if (l + off < 64) { A = fmaf(B, Ad, A); B *= Bd; }
    }
    float c = __shfl_down(A, 1);
    if (l == 63) c = 0.0f;
#pragma unroll
    for (int i = 0; i < WSEG; ++i) rls[rb + i] = fmaf(pl[i], c, yl[i]);
  }
  __syncthreads();

  // ---- fused final max + store (coalesced float4) ----
  float4* o4 = (float4*)(out + rowbase);
  {
    float4 a = rrv[i0], b = rlv[i0];
    float4 o;
    o.x = fmaxf(fmaxf(a.x, b.x), v0.x);
    o.y = fmaxf(fmaxf(a.y, b.y), v0.y);
    o.z = fmaxf(fmaxf(a.z, b.z), v0.z);
    o.w = fmaxf(fmaxf(a.w, b.w), v0.w);
    o4[i0] = o;
  }
  {
    float4 a = rrv[i1], b = rlv[i1];
    float4 o;
    o.x = fmaxf(fmaxf(a.x, b.x), v1.x);
    o.y = fmaxf(fmaxf(a.y, b.y), v1.y);
    o.z = fmaxf(fmaxf(a.z, b.z), v1.z);
    o.w = fmaxf(fmaxf(a.w, b.w), v1.w);
    o4[i1] = o;
  }
  if (i2 < Wn) {
    float4 a = rrv[i2], b = rlv[i2];
    float4 o;
    o.x = fmaxf(fmaxf(a.x, b.x), v2.x);
    o.y = fmaxf(fmaxf(a.y, b.y), v2.y);
    o.z = fmaxf(fmaxf(a.z, b.z), v2.z);
    o.w = fmaxf(fmaxf(a.w, b.w), v2.w);
    o4[i2] = o;
  }
}

extern "C" void kernel_launch(void* const* d_in, const int* in_sizes, int n_in,
                              void* d_out, int out_size, void* d_ws,
                              size_t ws_size, hipStream_t stream) {
  const float* x = (const float*)d_in[0];
  const float* g0 = (const float*)d_in[1];
  const float* g1 = (const float*)d_in[2];
  const float* g2 = (const float*)d_in[3];
  const float* g3 = (const float*)d_in[4];
  float* out = (float*)d_out;

  // vert_both writes max(r_down, r_up) into out (single store, both
  // directions fused in registers); horiz_final consumes it (block-local
  // lines) and overwrites with the final 4-way max. No ws use.
  vert_both<<<NCOL / 64, 1024, 0, stream>>>(x, g0, g1, out);
  horiz_final<<<NROW / 4, 256, 0, stream>>>(x, g2, g3, out, out);
}